// Round 5
// baseline (1783.716 us; speedup 1.0000x reference)
//
#include <hip/hip_runtime.h>
#include <math.h>

#define N 8192
#define NW 128          // 64-bit mask words per row
#define FIN 29
#define FH 8
#define NH 4
#define ALPHA 0.2f
#define LOG2E 1.4426950408889634f

typedef unsigned long long ull;

__device__ inline unsigned bf16rn(float f) {
    unsigned u = __float_as_uint(f);
    return (u + 0x7fffu + ((u >> 16) & 1u)) >> 16;
}
// unpack a uint32 holding two bf16 -> float2 {lo, hi}
__device__ inline float2 bfpair(unsigned u) {
    return make_float2(__uint_as_float(u << 16), __uint_as_float(u & 0xffff0000u));
}

// ---------------- K0: pack adj (256 MB int32) into bitmask (8 MB) ----------------
__global__ void k0_pack(const int* __restrict__ adj, ull* __restrict__ mask) {
    int row = blockIdx.x;
    int tid = threadIdx.x;
    int lane = tid & 63;
    int wave = tid >> 6;
    const int* rp = adj + (size_t)row * N;
#pragma unroll
    for (int i = 0; i < N / 1024; i++) {   // 8
        int a = rp[i * 1024 + tid];
        ull b = __ballot(a > 0);
        if (lane == 0) mask[(size_t)row * NW + i * 4 + wave] = b;
    }
}

// ---------------- K1: per-node features, scaled by log2(e); h packed to bf16 ----------------
__global__ __launch_bounds__(64) void k1_feat(
    const float* __restrict__ x, const float* __restrict__ Wh,
    const float* __restrict__ ah,
    float4* __restrict__ rec1f2, uint4* __restrict__ hpk,
    float* __restrict__ f1a) {
    __shared__ float sW[NH * FIN * FH];
    __shared__ float sa[NH * 2 * FH];
    int tid = threadIdx.x;
    for (int i = tid; i < NH * FIN * FH; i += 64) sW[i] = Wh[i];
    for (int i = tid; i < NH * 2 * FH; i += 64) sa[i] = ah[i];
    __syncthreads();
    int node = blockIdx.x * 64 + tid;
    if (node >= N) return;
    float xr[FIN];
#pragma unroll
    for (int f = 0; f < FIN; f++) xr[f] = x[node * FIN + f];
    float f2v[NH];
#pragma unroll
    for (int h = 0; h < NH; h++) {
        float hv[FH];
#pragma unroll
        for (int k = 0; k < FH; k++) {
            float s = 0.f;
#pragma unroll
            for (int f = 0; f < FIN; f++) s += xr[f] * sW[(h * FIN + f) * FH + k];
            hv[k] = s;
        }
        float f1 = 0.f, f2 = 0.f;
#pragma unroll
        for (int k = 0; k < FH; k++) {
            f1 += hv[k] * sa[h * 16 + k];
            f2 += hv[k] * sa[h * 16 + 8 + k];
        }
        f2v[h] = f2 * LOG2E;
        f1a[node * 4 + h] = f1 * LOG2E;
        uint4 p;
        p.x = (bf16rn(hv[1]) << 16) | bf16rn(hv[0]);
        p.y = (bf16rn(hv[3]) << 16) | bf16rn(hv[2]);
        p.z = (bf16rn(hv[5]) << 16) | bf16rn(hv[4]);
        p.w = (bf16rn(hv[7]) << 16) | bf16rn(hv[6]);
        hpk[h * N + node] = p;
    }
    rec1f2[node] = make_float4(f2v[0], f2v[1], f2v[2], f2v[3]);
}

// ---------------- K2: per-head global max of scaled f2 ----------------
__global__ __launch_bounds__(1024) void k2_max4(const float4* __restrict__ rec1f2,
                                                float* __restrict__ maxf2) {
    __shared__ float red[4][1024];
    int tid = threadIdx.x;
    float m[4] = {-1e30f, -1e30f, -1e30f, -1e30f};
    for (int j = tid; j < N; j += 1024) {
        float4 q = rec1f2[j];
        m[0] = fmaxf(m[0], q.x); m[1] = fmaxf(m[1], q.y);
        m[2] = fmaxf(m[2], q.z); m[3] = fmaxf(m[3], q.w);
    }
#pragma unroll
    for (int h = 0; h < 4; h++) red[h][tid] = m[h];
    __syncthreads();
    for (int s = 512; s > 0; s >>= 1) {
        if (tid < s) {
#pragma unroll
            for (int h = 0; h < 4; h++) red[h][tid] = fmaxf(red[h][tid], red[h][tid + s]);
        }
        __syncthreads();
    }
    if (tid < 4) maxf2[tid] = red[tid][0];
}

// ---------------- K3: layer-1 attention partials ----------------
// 512 thr = 8 waves x 2 rows = 16 rows/block; j split in 2 halves; grid 512*2
// NOTE: no tight launch_bounds — round 3/4 showed a (256,2)/(256,4) cap forces
// catastrophic scratch spill; the free 512-thread shape (round 2) parks the
// 80 fp32 accumulators in AGPRs (VGPR=92, zero scratch).
#define TJ 256
#define JS1 2
__global__ __launch_bounds__(512) void k3_attn1(
    const ull* __restrict__ mask, const float4* __restrict__ rec1f2,
    const uint4* __restrict__ hpk, const float* __restrict__ f1a,
    const float* __restrict__ maxf2, float* __restrict__ part1) {
    __shared__ uint4 tB[5][TJ];     // plane0 = f2 (bitcast), planes 1..4 = bf16 h; 20 KB
    int tid = threadIdx.x;
    int lane = tid & 63;
    int wave = tid >> 6;
    int rowblk = blockIdx.x >> 1;
    int js = blockIdx.x & 1;
    int r0 = rowblk * 16 + wave * 2;
    int r1 = r0 + 1;
    const int JR = N / JS1;          // 4096
    int jbase = js * JR;

    float f1m0[NH], f1q0[NH], f1m1[NH], f1q1[NH];
#pragma unroll
    for (int h = 0; h < NH; h++) {
        float mf = maxf2[h];
        float f1 = f1a[r0 * 4 + h];
        float v = f1 + mf, m = fmaxf(v, ALPHA * v);
        f1m0[h] = f1 - m; f1q0[h] = ALPHA * f1 - m;
        f1 = f1a[r1 * 4 + h];
        v = f1 + mf; m = fmaxf(v, ALPHA * v);
        f1m1[h] = f1 - m; f1q1[h] = ALPHA * f1 - m;
    }
    // float2 accumulators (pairs) to invite v_pk_fma_f32
    float2 acc0[NH][4], acc1[NH][4];
    float d0[NH], d1[NH];
#pragma unroll
    for (int h = 0; h < NH; h++) {
        d0[h] = 0.f; d1[h] = 0.f;
#pragma unroll
        for (int k = 0; k < 4; k++) {
            acc0[h][k] = make_float2(0.f, 0.f);
            acc1[h][k] = make_float2(0.f, 0.f);
        }
    }
    const ull* mr0 = mask + (size_t)r0 * NW;
    const ull* mr1 = mask + (size_t)r1 * NW;
    const uint4* rfu = (const uint4*)rec1f2;

    for (int t = 0; t < JR / TJ; t++) {   // 16
        __syncthreads();
        for (int i = tid; i < 5 * TJ; i += 512) {
            int pl = i >> 8;
            int idx = i & (TJ - 1);
            uint4 v;
            if (pl == 0) v = rfu[jbase + t * TJ + idx];
            else        v = hpk[(pl - 1) * N + jbase + t * TJ + idx];
            tB[pl][idx] = v;
        }
        __syncthreads();
        int wb = (jbase >> 6) + t * (TJ / 64);
        ull mwa0[TJ / 64], mwa1[TJ / 64];
#pragma unroll
        for (int s = 0; s < TJ / 64; s++) { mwa0[s] = mr0[wb + s]; mwa1[s] = mr1[wb + s]; }
#pragma unroll
        for (int s = 0; s < TJ / 64; s++) {   // 4
            bool b0 = (mwa0[s] >> lane) & 1ull;
            bool b1 = (mwa1[s] >> lane) & 1ull;
            int jl = s * 64 + lane;
            uint4 qf = tB[0][jl];
            float f2h[4] = {__uint_as_float(qf.x), __uint_as_float(qf.y),
                            __uint_as_float(qf.z), __uint_as_float(qf.w)};
#pragma unroll
            for (int h = 0; h < NH; h++) {
                uint4 q = tB[1 + h][jl];
                float2 hv01 = bfpair(q.x);
                float2 hv23 = bfpair(q.y);
                float2 hv45 = bfpair(q.z);
                float2 hv67 = bfpair(q.w);
                float p = ALPHA * f2h[h];
                float t1 = f1m0[h] + f2h[h];
                float t2 = p + f1q0[h];
                float w0 = __builtin_amdgcn_exp2f(fmaxf(t1, t2));
                w0 = b0 ? w0 : 0.f;
                float u1 = f1m1[h] + f2h[h];
                float u2 = p + f1q1[h];
                float w1 = __builtin_amdgcn_exp2f(fmaxf(u1, u2));
                w1 = b1 ? w1 : 0.f;
                acc0[h][0].x = fmaf(w0, hv01.x, acc0[h][0].x);
                acc0[h][0].y = fmaf(w0, hv01.y, acc0[h][0].y);
                acc0[h][1].x = fmaf(w0, hv23.x, acc0[h][1].x);
                acc0[h][1].y = fmaf(w0, hv23.y, acc0[h][1].y);
                acc0[h][2].x = fmaf(w0, hv45.x, acc0[h][2].x);
                acc0[h][2].y = fmaf(w0, hv45.y, acc0[h][2].y);
                acc0[h][3].x = fmaf(w0, hv67.x, acc0[h][3].x);
                acc0[h][3].y = fmaf(w0, hv67.y, acc0[h][3].y);
                d0[h] += w0;
                acc1[h][0].x = fmaf(w1, hv01.x, acc1[h][0].x);
                acc1[h][0].y = fmaf(w1, hv01.y, acc1[h][0].y);
                acc1[h][1].x = fmaf(w1, hv23.x, acc1[h][1].x);
                acc1[h][1].y = fmaf(w1, hv23.y, acc1[h][1].y);
                acc1[h][2].x = fmaf(w1, hv45.x, acc1[h][2].x);
                acc1[h][2].y = fmaf(w1, hv45.y, acc1[h][2].y);
                acc1[h][3].x = fmaf(w1, hv67.x, acc1[h][3].x);
                acc1[h][3].y = fmaf(w1, hv67.y, acc1[h][3].y);
                d1[h] += w1;
            }
        }
    }
#pragma unroll
    for (int h = 0; h < NH; h++) {
#pragma unroll
        for (int k = 0; k < 4; k++) {
            for (int off = 32; off > 0; off >>= 1) {
                acc0[h][k].x += __shfl_xor(acc0[h][k].x, off, 64);
                acc0[h][k].y += __shfl_xor(acc0[h][k].y, off, 64);
                acc1[h][k].x += __shfl_xor(acc1[h][k].x, off, 64);
                acc1[h][k].y += __shfl_xor(acc1[h][k].y, off, 64);
            }
        }
        for (int off = 32; off > 0; off >>= 1) {
            d0[h] += __shfl_xor(d0[h], off, 64);
            d1[h] += __shfl_xor(d1[h], off, 64);
        }
    }
    if (lane == 0) {
#pragma unroll
        for (int h = 0; h < NH; h++) {
#pragma unroll
            for (int k = 0; k < 4; k++) {
                part1[(js * 36 + h * 9 + 2 * k + 0) * N + r0] = acc0[h][k].x;
                part1[(js * 36 + h * 9 + 2 * k + 1) * N + r0] = acc0[h][k].y;
                part1[(js * 36 + h * 9 + 2 * k + 0) * N + r1] = acc1[h][k].x;
                part1[(js * 36 + h * 9 + 2 * k + 1) * N + r1] = acc1[h][k].y;
            }
            part1[(js * 36 + h * 9 + 8) * N + r0] = d0[h];
            part1[(js * 36 + h * 9 + 8) * N + r1] = d1[h];
        }
    }
}

// ---------------- K3b: finalize layer 1 (normalize+elu) fused with layer-2 features ----------------
__global__ void k3b_final(const float* __restrict__ part1, const float* __restrict__ Wo,
                          const float* __restrict__ ao,
                          float4* __restrict__ rec2, float* __restrict__ f1b) {
    __shared__ float sW[64];
    __shared__ float sa[4];
    int tid = threadIdx.x;
    if (tid < 64) sW[tid] = Wo[tid];
    if (tid < 4) sa[tid] = ao[tid];
    __syncthreads();
    int row = blockIdx.x * 256 + tid;
    float hv[32];
#pragma unroll
    for (int h = 0; h < NH; h++) {
        float s[9];
#pragma unroll
        for (int c = 0; c < 9; c++)
            s[c] = part1[(h * 9 + c) * N + row] + part1[(36 + h * 9 + c) * N + row];
        float inv = 1.f / s[8];
#pragma unroll
        for (int k = 0; k < FH; k++) {
            float o = s[k] * inv;
            hv[h * 8 + k] = (o > 0.f) ? o : expm1f(o);
        }
    }
    float h0 = 0.f, h1 = 0.f;
#pragma unroll
    for (int i = 0; i < 32; i++) {
        h0 = fmaf(hv[i], sW[i * 2 + 0], h0);
        h1 = fmaf(hv[i], sW[i * 2 + 1], h1);
    }
    float f1 = (h0 * sa[0] + h1 * sa[1]) * LOG2E;
    float f2 = (h0 * sa[2] + h1 * sa[3]) * LOG2E;
    rec2[row] = make_float4(f2, h0, h1, 0.f);
    f1b[row] = f1;
}

// ---------------- K5: global max of scaled f2 (layer 2) ----------------
__global__ __launch_bounds__(1024) void k5_max1(const float4* __restrict__ rec2,
                                                float* __restrict__ maxf2b) {
    __shared__ float red[1024];
    int tid = threadIdx.x;
    float m = -1e30f;
    for (int j = tid; j < N; j += 1024) m = fmaxf(m, rec2[j].x);
    red[tid] = m;
    __syncthreads();
    for (int s = 512; s > 0; s >>= 1) {
        if (tid < s) red[tid] = fmaxf(red[tid], red[tid + s]);
        __syncthreads();
    }
    if (tid == 0) maxf2b[0] = red[0];
}

// ---------------- K6: layer-2 attention partials ----------------
// 256 thr = 4 waves x 4 rows = 16 rows/block; j split in 4; grid 512*4
#define TJ2 256
#define JS2 4
__global__ __launch_bounds__(256) void k6_attn2(
    const ull* __restrict__ mask, const float4* __restrict__ rec2,
    const float* __restrict__ f1b, const float* __restrict__ maxf2b,
    float* __restrict__ part2) {
    __shared__ float4 tile[TJ2];   // 4 KB
    int tid = threadIdx.x;
    int lane = tid & 63;
    int wave = tid >> 6;
    int blk = blockIdx.x >> 2;
    int js = blockIdx.x & 3;
    int rbase = blk * 16 + wave * 4;
    const int JR = N / JS2;   // 2048
    int jbase = js * JR;

    float mb = maxf2b[0];
    float f1m[4], f1q[4];
#pragma unroll
    for (int i = 0; i < 4; i++) {
        float f1 = f1b[rbase + i];
        float v = f1 + mb, m = fmaxf(v, ALPHA * v);
        f1m[i] = f1 - m; f1q[i] = ALPHA * f1 - m;
    }
    float a0[4] = {0.f, 0.f, 0.f, 0.f};
    float a1[4] = {0.f, 0.f, 0.f, 0.f};
    float dd[4] = {0.f, 0.f, 0.f, 0.f};
    const ull* mr[4];
#pragma unroll
    for (int i = 0; i < 4; i++) mr[i] = mask + (size_t)(rbase + i) * NW;

    for (int t = 0; t < JR / TJ2; t++) {   // 8
        __syncthreads();
        tile[tid] = rec2[jbase + t * TJ2 + tid];
        __syncthreads();
        int wb = (jbase >> 6) + t * (TJ2 / 64);
        ull mw[4][TJ2 / 64];
#pragma unroll
        for (int i = 0; i < 4; i++)
#pragma unroll
            for (int s = 0; s < TJ2 / 64; s++) mw[i][s] = mr[i][wb + s];
#pragma unroll
        for (int s = 0; s < TJ2 / 64; s++) {   // 4
            float4 q = tile[s * 64 + lane];
            float p = ALPHA * q.x;
#pragma unroll
            for (int i = 0; i < 4; i++) {
                float t1 = f1m[i] + q.x;
                float t2 = p + f1q[i];
                float w = __builtin_amdgcn_exp2f(fmaxf(t1, t2));
                w = ((mw[i][s] >> lane) & 1ull) ? w : 0.f;
                a0[i] = fmaf(w, q.y, a0[i]);
                a1[i] = fmaf(w, q.z, a1[i]);
                dd[i] += w;
            }
        }
    }
#pragma unroll
    for (int i = 0; i < 4; i++) {
        for (int off = 32; off > 0; off >>= 1) {
            a0[i] += __shfl_xor(a0[i], off, 64);
            a1[i] += __shfl_xor(a1[i], off, 64);
            dd[i] += __shfl_xor(dd[i], off, 64);
        }
    }
    if (lane == 0) {
#pragma unroll
        for (int i = 0; i < 4; i++) {
            int row = rbase + i;
            part2[(js * 3 + 0) * N + row] = a0[i];
            part2[(js * 3 + 1) * N + row] = a1[i];
            part2[(js * 3 + 2) * N + row] = dd[i];
        }
    }
}

// ---------------- K6b: finalize layer 2 + log_softmax ----------------
__global__ void k6b_final(const float* __restrict__ part2, float* __restrict__ out) {
    int row = blockIdx.x * 256 + threadIdx.x;
    float s0 = 0.f, s1 = 0.f, d = 0.f;
#pragma unroll
    for (int js = 0; js < JS2; js++) {
        s0 += part2[(js * 3 + 0) * N + row];
        s1 += part2[(js * 3 + 1) * N + row];
        d  += part2[(js * 3 + 2) * N + row];
    }
    float inv = 1.f / d;
    float e0 = s0 * inv, e1 = s1 * inv;
    e0 = (e0 > 0.f) ? e0 : expm1f(e0);
    e1 = (e1 > 0.f) ? e1 : expm1f(e1);
    float mx = fmaxf(e0, e1);
    float lse = mx + logf(expf(e0 - mx) + expf(e1 - mx));
    ((float2*)out)[row] = make_float2(e0 - lse, e1 - lse);
}

extern "C" void kernel_launch(void* const* d_in, const int* in_sizes, int n_in,
                              void* d_out, int out_size, void* d_ws, size_t ws_size,
                              hipStream_t stream) {
    const float* x   = (const float*)d_in[0];
    const int*   adj = (const int*)d_in[1];
    const float* Wh  = (const float*)d_in[2];
    const float* ah  = (const float*)d_in[3];
    const float* Wo  = (const float*)d_in[4];
    const float* ao  = (const float*)d_in[5];
    float* out = (float*)d_out;
    float* ws = (float*)d_ws;

    // workspace layout (float offsets)
    ull*    mask   = (ull*)ws;                        // 8 MB = 2097152 floats
    float4* rec1f2 = (float4*)(ws + 2097152);         // N float4
    uint4*  hpk    = (uint4*)(ws + 2129920);          // 4*N uint4
    float*  f1a    = ws + 2260992;                    // 4*N
    float*  part1  = ws + 2293760;                    // 2*36*N = 589824
    float4* rec2   = (float4*)(ws + 2883584);         // N float4
    float*  f1b    = ws + 2916352;                    // N
    float*  part2  = ws + 2924544;                    // 12*N = 98304
    float*  mf2    = ws + 3022848;                    // 4
    float*  mf2b   = ws + 3022852;                    // 1

    k0_pack<<<N, 256, 0, stream>>>(adj, mask);
    k1_feat<<<N / 64, 64, 0, stream>>>(x, Wh, ah, rec1f2, hpk, f1a);
    k2_max4<<<1, 1024, 0, stream>>>(rec1f2, mf2);
    k3_attn1<<<(N / 16) * JS1, 512, 0, stream>>>(mask, rec1f2, hpk, f1a, mf2, part1);
    k3b_final<<<N / 256, 256, 0, stream>>>(part1, Wo, ao, rec2, f1b);
    k5_max1<<<1, 1024, 0, stream>>>(rec2, mf2b);
    k6_attn2<<<(N / 16) * JS2, 256, 0, stream>>>(mask, rec2, f1b, mf2b, part2);
    k6b_final<<<N / 256, 256, 0, stream>>>(part2, out);
}

// Round 6
// 1617.378 us; speedup vs baseline: 1.1028x; 1.1028x over previous
//
#include <hip/hip_runtime.h>
#include <math.h>

#define N 8192
#define NW 128          // 64-bit mask words per row
#define FIN 29
#define FH 8
#define NH 4
#define ALPHA 0.2f
#define LOG2E 1.4426950408889634f

typedef unsigned long long ull;

__device__ inline unsigned bf16rn(float f) {
    unsigned u = __float_as_uint(f);
    return (u + 0x7fffu + ((u >> 16) & 1u)) >> 16;
}
// unpack a uint32 holding two bf16 -> float2 {lo, hi}
__device__ inline float2 bfpair(unsigned u) {
    return make_float2(__uint_as_float(u << 16), __uint_as_float(u & 0xffff0000u));
}

// ---------------- K0: pack adj (256 MB int32) into bitmask (8 MB) ----------------
__global__ void k0_pack(const int* __restrict__ adj, ull* __restrict__ mask) {
    int row = blockIdx.x;
    int tid = threadIdx.x;
    int lane = tid & 63;
    int wave = tid >> 6;
    const int* rp = adj + (size_t)row * N;
#pragma unroll
    for (int i = 0; i < N / 1024; i++) {   // 8
        int a = rp[i * 1024 + tid];
        ull b = __ballot(a > 0);
        if (lane == 0) mask[(size_t)row * NW + i * 4 + wave] = b;
    }
}

// ---------------- K1: per-node features; f2 stored as per-head planes; h packed bf16 ----------------
__global__ __launch_bounds__(64) void k1_feat(
    const float* __restrict__ x, const float* __restrict__ Wh,
    const float* __restrict__ ah,
    float* __restrict__ f2p, uint4* __restrict__ hpk,
    float* __restrict__ f1a) {
    __shared__ float sW[NH * FIN * FH];
    __shared__ float sa[NH * 2 * FH];
    int tid = threadIdx.x;
    for (int i = tid; i < NH * FIN * FH; i += 64) sW[i] = Wh[i];
    for (int i = tid; i < NH * 2 * FH; i += 64) sa[i] = ah[i];
    __syncthreads();
    int node = blockIdx.x * 64 + tid;
    if (node >= N) return;
    float xr[FIN];
#pragma unroll
    for (int f = 0; f < FIN; f++) xr[f] = x[node * FIN + f];
#pragma unroll
    for (int h = 0; h < NH; h++) {
        float hv[FH];
#pragma unroll
        for (int k = 0; k < FH; k++) {
            float s = 0.f;
#pragma unroll
            for (int f = 0; f < FIN; f++) s += xr[f] * sW[(h * FIN + f) * FH + k];
            hv[k] = s;
        }
        float f1 = 0.f, f2 = 0.f;
#pragma unroll
        for (int k = 0; k < FH; k++) {
            f1 += hv[k] * sa[h * 16 + k];
            f2 += hv[k] * sa[h * 16 + 8 + k];
        }
        f2p[h * N + node] = f2 * LOG2E;
        f1a[node * 4 + h] = f1 * LOG2E;
        uint4 p;
        p.x = (bf16rn(hv[1]) << 16) | bf16rn(hv[0]);
        p.y = (bf16rn(hv[3]) << 16) | bf16rn(hv[2]);
        p.z = (bf16rn(hv[5]) << 16) | bf16rn(hv[4]);
        p.w = (bf16rn(hv[7]) << 16) | bf16rn(hv[6]);
        hpk[h * N + node] = p;
    }
}

// ---------------- K2: per-head global max of scaled f2 ----------------
__global__ __launch_bounds__(1024) void k2_max4(const float* __restrict__ f2p,
                                                float* __restrict__ maxf2) {
    __shared__ float red[4][1024];
    int tid = threadIdx.x;
    float m[4] = {-1e30f, -1e30f, -1e30f, -1e30f};
    for (int j = tid; j < N; j += 1024) {
#pragma unroll
        for (int h = 0; h < 4; h++) m[h] = fmaxf(m[h], f2p[h * N + j]);
    }
#pragma unroll
    for (int h = 0; h < 4; h++) red[h][tid] = m[h];
    __syncthreads();
    for (int s = 512; s > 0; s >>= 1) {
        if (tid < s) {
#pragma unroll
            for (int h = 0; h < 4; h++) red[h][tid] = fmaxf(red[h][tid], red[h][tid + s]);
        }
        __syncthreads();
    }
    if (tid < 4) maxf2[tid] = red[tid][0];
}

// ---------------- K3: layer-1 attention partials, HEAD-SPLIT ----------------
// Each block: 8 waves x 2 rows = 16 rows, but only 2 of the 4 heads.
// Register budget: 36 accs + 8 consts + ~30 temps  (~75-95 VGPR -> no spill tier).
// blockIdx.x = ((rowblk * JS1) + js) * 2 + hp ; grid = (N/16)*JS1*2 = 2048
#define TJ 512
#define JS1 2
__global__ __launch_bounds__(512) void k3_attn1(
    const ull* __restrict__ mask, const float* __restrict__ f2p,
    const uint4* __restrict__ hpk, const float* __restrict__ f1a,
    const float* __restrict__ maxf2, float* __restrict__ part1) {
    __shared__ float tF2[2][TJ];   // 4 KB
    __shared__ uint4 tH[2][TJ];    // 16 KB
    int tid = threadIdx.x;
    int lane = tid & 63;
    int wave = tid >> 6;
    int hp = blockIdx.x & 1;
    int js = (blockIdx.x >> 1) & 1;
    int rowblk = blockIdx.x >> 2;
    int r0 = rowblk * 16 + wave * 2;
    int r1 = r0 + 1;
    int ha = 2 * hp, hb = 2 * hp + 1;     // the two heads this block owns
    const int JR = N / JS1;               // 4096
    int jbase = js * JR;

    // per-(row,q) constants, exp2-folded
    float f1m[2][2], f1q[2][2];
#pragma unroll
    for (int r = 0; r < 2; r++) {
        int row = r ? r1 : r0;
#pragma unroll
        for (int q = 0; q < 2; q++) {
            int h = 2 * hp + q;
            float mf = maxf2[h];
            float f1 = f1a[row * 4 + h];
            float v = f1 + mf, m = fmaxf(v, ALPHA * v);
            f1m[r][q] = f1 - m;
            f1q[r][q] = ALPHA * f1 - m;
        }
    }
    float acc[2][2][FH];     // [row][q][k]
    float dsum[2][2];
#pragma unroll
    for (int r = 0; r < 2; r++)
#pragma unroll
        for (int q = 0; q < 2; q++) {
            dsum[r][q] = 0.f;
#pragma unroll
            for (int k = 0; k < FH; k++) acc[r][q][k] = 0.f;
        }
    const ull* mr0 = mask + (size_t)r0 * NW;
    const ull* mr1 = mask + (size_t)r1 * NW;

    for (int t = 0; t < JR / TJ; t++) {   // 8
        __syncthreads();
        int gb = jbase + t * TJ + tid;
        tH[0][tid] = hpk[ha * N + gb];
        tH[1][tid] = hpk[hb * N + gb];
        tF2[0][tid] = f2p[ha * N + gb];
        tF2[1][tid] = f2p[hb * N + gb];
        __syncthreads();
        int wb = (jbase >> 6) + t * (TJ / 64);
#pragma unroll
        for (int s = 0; s < TJ / 64; s++) {   // 8
            ull mw0 = mr0[wb + s];
            ull mw1 = mr1[wb + s];
            bool b0 = (mw0 >> lane) & 1ull;
            bool b1 = (mw1 >> lane) & 1ull;
            int jl = s * 64 + lane;
#pragma unroll
            for (int q = 0; q < 2; q++) {
                float f2 = tF2[q][jl];
                uint4 hq = tH[q][jl];
                float2 hv01 = bfpair(hq.x);
                float2 hv23 = bfpair(hq.y);
                float2 hv45 = bfpair(hq.z);
                float2 hv67 = bfpair(hq.w);
                float p = ALPHA * f2;
                float w0 = __builtin_amdgcn_exp2f(fmaxf(f1m[0][q] + f2, p + f1q[0][q]));
                w0 = b0 ? w0 : 0.f;
                float w1 = __builtin_amdgcn_exp2f(fmaxf(f1m[1][q] + f2, p + f1q[1][q]));
                w1 = b1 ? w1 : 0.f;
                acc[0][q][0] = fmaf(w0, hv01.x, acc[0][q][0]);
                acc[0][q][1] = fmaf(w0, hv01.y, acc[0][q][1]);
                acc[0][q][2] = fmaf(w0, hv23.x, acc[0][q][2]);
                acc[0][q][3] = fmaf(w0, hv23.y, acc[0][q][3]);
                acc[0][q][4] = fmaf(w0, hv45.x, acc[0][q][4]);
                acc[0][q][5] = fmaf(w0, hv45.y, acc[0][q][5]);
                acc[0][q][6] = fmaf(w0, hv67.x, acc[0][q][6]);
                acc[0][q][7] = fmaf(w0, hv67.y, acc[0][q][7]);
                dsum[0][q] += w0;
                acc[1][q][0] = fmaf(w1, hv01.x, acc[1][q][0]);
                acc[1][q][1] = fmaf(w1, hv01.y, acc[1][q][1]);
                acc[1][q][2] = fmaf(w1, hv23.x, acc[1][q][2]);
                acc[1][q][3] = fmaf(w1, hv23.y, acc[1][q][3]);
                acc[1][q][4] = fmaf(w1, hv45.x, acc[1][q][4]);
                acc[1][q][5] = fmaf(w1, hv45.y, acc[1][q][5]);
                acc[1][q][6] = fmaf(w1, hv67.x, acc[1][q][6]);
                acc[1][q][7] = fmaf(w1, hv67.y, acc[1][q][7]);
                dsum[1][q] += w1;
            }
        }
    }
#pragma unroll
    for (int r = 0; r < 2; r++)
#pragma unroll
        for (int q = 0; q < 2; q++) {
#pragma unroll
            for (int k = 0; k < FH; k++)
                for (int off = 32; off > 0; off >>= 1)
                    acc[r][q][k] += __shfl_xor(acc[r][q][k], off, 64);
            for (int off = 32; off > 0; off >>= 1)
                dsum[r][q] += __shfl_xor(dsum[r][q], off, 64);
        }
    if (lane == 0) {
#pragma unroll
        for (int r = 0; r < 2; r++) {
            int row = r ? r1 : r0;
#pragma unroll
            for (int q = 0; q < 2; q++) {
                int h = 2 * hp + q;
#pragma unroll
                for (int k = 0; k < FH; k++)
                    part1[(js * 36 + h * 9 + k) * N + row] = acc[r][q][k];
                part1[(js * 36 + h * 9 + 8) * N + row] = dsum[r][q];
            }
        }
    }
}

// ---------------- K3b: finalize layer 1 (normalize+elu) fused with layer-2 features ----------------
__global__ void k3b_final(const float* __restrict__ part1, const float* __restrict__ Wo,
                          const float* __restrict__ ao,
                          float4* __restrict__ rec2, float* __restrict__ f1b) {
    __shared__ float sW[64];
    __shared__ float sa[4];
    int tid = threadIdx.x;
    if (tid < 64) sW[tid] = Wo[tid];
    if (tid < 4) sa[tid] = ao[tid];
    __syncthreads();
    int row = blockIdx.x * 256 + tid;
    float hv[32];
#pragma unroll
    for (int h = 0; h < NH; h++) {
        float s[9];
#pragma unroll
        for (int c = 0; c < 9; c++)
            s[c] = part1[(h * 9 + c) * N + row] + part1[(36 + h * 9 + c) * N + row];
        float inv = 1.f / s[8];
#pragma unroll
        for (int k = 0; k < FH; k++) {
            float o = s[k] * inv;
            hv[h * 8 + k] = (o > 0.f) ? o : expm1f(o);
        }
    }
    float h0 = 0.f, h1 = 0.f;
#pragma unroll
    for (int i = 0; i < 32; i++) {
        h0 = fmaf(hv[i], sW[i * 2 + 0], h0);
        h1 = fmaf(hv[i], sW[i * 2 + 1], h1);
    }
    float f1 = (h0 * sa[0] + h1 * sa[1]) * LOG2E;
    float f2 = (h0 * sa[2] + h1 * sa[3]) * LOG2E;
    rec2[row] = make_float4(f2, h0, h1, 0.f);
    f1b[row] = f1;
}

// ---------------- K5: global max of scaled f2 (layer 2) ----------------
__global__ __launch_bounds__(1024) void k5_max1(const float4* __restrict__ rec2,
                                                float* __restrict__ maxf2b) {
    __shared__ float red[1024];
    int tid = threadIdx.x;
    float m = -1e30f;
    for (int j = tid; j < N; j += 1024) m = fmaxf(m, rec2[j].x);
    red[tid] = m;
    __syncthreads();
    for (int s = 512; s > 0; s >>= 1) {
        if (tid < s) red[tid] = fmaxf(red[tid], red[tid + s]);
        __syncthreads();
    }
    if (tid == 0) maxf2b[0] = red[0];
}

// ---------------- K6: layer-2 attention partials — no LDS, no barriers ----------------
// rec2 (128 KB) is L2-resident: stream float4 straight from global.
// 256 thr = 4 waves x 4 rows = 16 rows/block; j split in 4; grid 512*4
#define JS2 4
__global__ __launch_bounds__(256) void k6_attn2(
    const ull* __restrict__ mask, const float4* __restrict__ rec2,
    const float* __restrict__ f1b, const float* __restrict__ maxf2b,
    float* __restrict__ part2) {
    int tid = threadIdx.x;
    int lane = tid & 63;
    int wave = tid >> 6;
    int blk = blockIdx.x >> 2;
    int js = blockIdx.x & 3;
    int rbase = blk * 16 + wave * 4;
    const int JR = N / JS2;   // 2048
    int jbase = js * JR;

    float mb = maxf2b[0];
    float f1m[4], f1q[4];
#pragma unroll
    for (int i = 0; i < 4; i++) {
        float f1 = f1b[rbase + i];
        float v = f1 + mb, m = fmaxf(v, ALPHA * v);
        f1m[i] = f1 - m; f1q[i] = ALPHA * f1 - m;
    }
    float a0[4] = {0.f, 0.f, 0.f, 0.f};
    float a1[4] = {0.f, 0.f, 0.f, 0.f};
    float dd[4] = {0.f, 0.f, 0.f, 0.f};
    const ull* mr[4];
#pragma unroll
    for (int i = 0; i < 4; i++) mr[i] = mask + (size_t)(rbase + i) * NW;

    int wb = jbase >> 6;
#pragma unroll 4
    for (int s = 0; s < JR / 64; s++) {   // 32
        float4 q = rec2[jbase + s * 64 + lane];
        float p = ALPHA * q.x;
#pragma unroll
        for (int i = 0; i < 4; i++) {
            ull mw = mr[i][wb + s];
            float w = __builtin_amdgcn_exp2f(fmaxf(f1m[i] + q.x, p + f1q[i]));
            w = ((mw >> lane) & 1ull) ? w : 0.f;
            a0[i] = fmaf(w, q.y, a0[i]);
            a1[i] = fmaf(w, q.z, a1[i]);
            dd[i] += w;
        }
    }
#pragma unroll
    for (int i = 0; i < 4; i++) {
        for (int off = 32; off > 0; off >>= 1) {
            a0[i] += __shfl_xor(a0[i], off, 64);
            a1[i] += __shfl_xor(a1[i], off, 64);
            dd[i] += __shfl_xor(dd[i], off, 64);
        }
    }
    if (lane == 0) {
#pragma unroll
        for (int i = 0; i < 4; i++) {
            int row = rbase + i;
            part2[(js * 3 + 0) * N + row] = a0[i];
            part2[(js * 3 + 1) * N + row] = a1[i];
            part2[(js * 3 + 2) * N + row] = dd[i];
        }
    }
}

// ---------------- K6b: finalize layer 2 + log_softmax ----------------
__global__ void k6b_final(const float* __restrict__ part2, float* __restrict__ out) {
    int row = blockIdx.x * 256 + threadIdx.x;
    float s0 = 0.f, s1 = 0.f, d = 0.f;
#pragma unroll
    for (int js = 0; js < JS2; js++) {
        s0 += part2[(js * 3 + 0) * N + row];
        s1 += part2[(js * 3 + 1) * N + row];
        d  += part2[(js * 3 + 2) * N + row];
    }
    float inv = 1.f / d;
    float e0 = s0 * inv, e1 = s1 * inv;
    e0 = (e0 > 0.f) ? e0 : expm1f(e0);
    e1 = (e1 > 0.f) ? e1 : expm1f(e1);
    float mx = fmaxf(e0, e1);
    float lse = mx + logf(expf(e0 - mx) + expf(e1 - mx));
    ((float2*)out)[row] = make_float2(e0 - lse, e1 - lse);
}

extern "C" void kernel_launch(void* const* d_in, const int* in_sizes, int n_in,
                              void* d_out, int out_size, void* d_ws, size_t ws_size,
                              hipStream_t stream) {
    const float* x   = (const float*)d_in[0];
    const int*   adj = (const int*)d_in[1];
    const float* Wh  = (const float*)d_in[2];
    const float* ah  = (const float*)d_in[3];
    const float* Wo  = (const float*)d_in[4];
    const float* ao  = (const float*)d_in[5];
    float* out = (float*)d_out;
    float* ws = (float*)d_ws;

    // workspace layout (float offsets)
    ull*    mask   = (ull*)ws;                        // 8 MB = 2097152 floats
    float*  f2p    = ws + 2097152;                    // 4*N
    uint4*  hpk    = (uint4*)(ws + 2129920);          // 4*N uint4 = 131072 floats
    float*  f1a    = ws + 2260992;                    // 4*N
    float*  part1  = ws + 2293760;                    // 2*36*N = 589824
    float4* rec2   = (float4*)(ws + 2883584);         // N float4
    float*  f1b    = ws + 2916352;                    // N
    float*  part2  = ws + 2924544;                    // 12*N = 98304
    float*  mf2    = ws + 3022848;                    // 4
    float*  mf2b   = ws + 3022852;                    // 1

    k0_pack<<<N, 256, 0, stream>>>(adj, mask);
    k1_feat<<<N / 64, 64, 0, stream>>>(x, Wh, ah, f2p, hpk, f1a);
    k2_max4<<<1, 1024, 0, stream>>>(f2p, mf2);
    k3_attn1<<<(N / 16) * JS1 * 2, 512, 0, stream>>>(mask, f2p, hpk, f1a, mf2, part1);
    k3b_final<<<N / 256, 256, 0, stream>>>(part1, Wo, ao, rec2, f1b);
    k5_max1<<<1, 1024, 0, stream>>>(rec2, mf2b);
    k6_attn2<<<(N / 16) * JS2, 256, 0, stream>>>(mask, rec2, f1b, mf2b, part2);
    k6b_final<<<N / 256, 256, 0, stream>>>(part2, out);
}

// Round 7
// 618.821 us; speedup vs baseline: 2.8824x; 2.6136x over previous
//
#include <hip/hip_runtime.h>
#include <math.h>

#define N 8192
#define NW 128          // 64-bit mask words per row
#define FIN 29
#define FH 8
#define NH 4
#define ALPHA 0.2f
#define LOG2E 1.4426950408889634f

typedef unsigned long long ull;

__device__ inline unsigned bf16rn(float f) {
    unsigned u = __float_as_uint(f);
    return (u + 0x7fffu + ((u >> 16) & 1u)) >> 16;
}
// unpack a uint32 holding two bf16 -> float2 {lo, hi}
__device__ inline float2 bfpair(unsigned u) {
    return make_float2(__uint_as_float(u << 16), __uint_as_float(u & 0xffff0000u));
}
// monotone float <-> unsigned encoding for atomicMax
__device__ inline unsigned fenc(float x) {
    unsigned u = __float_as_uint(x);
    return (u & 0x80000000u) ? ~u : (u | 0x80000000u);
}
__device__ inline float fdec(unsigned e) {
    return __uint_as_float((e & 0x80000000u) ? (e & 0x7fffffffu) : ~e);
}

// ---------------- K0: pack adj (256 MB int32) into bitmask (8 MB) ----------------
// FIXED: previous version read only 1/4 of each row and left words 32..127 poisoned.
// bit of word w=(i*4+wave), lane  <->  element i*256 + wave*64 + lane = i*256+tid. ✓
__global__ void k0_pack(const int* __restrict__ adj, ull* __restrict__ mask,
                        unsigned* __restrict__ amax) {
    int row = blockIdx.x;
    int tid = threadIdx.x;
    int lane = tid & 63;
    int wave = tid >> 6;
    if (row == 0 && tid < 8) amax[tid] = 0u;   // init atomic-max slots (k1 runs next)
    const int* rp = adj + (size_t)row * N;
#pragma unroll 8
    for (int i = 0; i < 32; i++) {
        int a = rp[i * 256 + tid];
        ull b = __ballot(a > 0);
        if (lane == 0) mask[(size_t)row * NW + i * 4 + wave] = b;
    }
}

// ---------------- K1: per-node features; f2 per-head planes; h packed bf16; fused max ----------------
__global__ __launch_bounds__(64) void k1_feat(
    const float* __restrict__ x, const float* __restrict__ Wh,
    const float* __restrict__ ah,
    float* __restrict__ f2p, uint4* __restrict__ hpk,
    float* __restrict__ f1a, unsigned* __restrict__ amax) {
    __shared__ float sW[NH * FIN * FH];
    __shared__ float sa[NH * 2 * FH];
    int tid = threadIdx.x;
    for (int i = tid; i < NH * FIN * FH; i += 64) sW[i] = Wh[i];
    for (int i = tid; i < NH * 2 * FH; i += 64) sa[i] = ah[i];
    __syncthreads();
    int node = blockIdx.x * 64 + tid;   // N % 64 == 0: all threads valid
    float xr[FIN];
#pragma unroll
    for (int f = 0; f < FIN; f++) xr[f] = x[node * FIN + f];
    float f2v[NH];
#pragma unroll
    for (int h = 0; h < NH; h++) {
        float hv[FH];
#pragma unroll
        for (int k = 0; k < FH; k++) {
            float s = 0.f;
#pragma unroll
            for (int f = 0; f < FIN; f++) s += xr[f] * sW[(h * FIN + f) * FH + k];
            hv[k] = s;
        }
        float f1 = 0.f, f2 = 0.f;
#pragma unroll
        for (int k = 0; k < FH; k++) {
            f1 += hv[k] * sa[h * 16 + k];
            f2 += hv[k] * sa[h * 16 + 8 + k];
        }
        f2v[h] = f2 * LOG2E;
        f2p[h * N + node] = f2v[h];
        f1a[node * 4 + h] = f1 * LOG2E;
        uint4 p;
        p.x = (bf16rn(hv[1]) << 16) | bf16rn(hv[0]);
        p.y = (bf16rn(hv[3]) << 16) | bf16rn(hv[2]);
        p.z = (bf16rn(hv[5]) << 16) | bf16rn(hv[4]);
        p.w = (bf16rn(hv[7]) << 16) | bf16rn(hv[6]);
        hpk[h * N + node] = p;
    }
    // fused per-head global max (wave-reduce then 1 atomic per head)
#pragma unroll
    for (int h = 0; h < NH; h++) {
        float v = f2v[h];
        for (int off = 32; off > 0; off >>= 1) v = fmaxf(v, __shfl_xor(v, off, 64));
        if (tid == 0) atomicMax(&amax[h], fenc(v));
    }
}

// ---------------- K3: layer-1 attention partials — 1 HEAD per block, 2 rows per wave ----------------
// Per-wave live state: 18 accs + 4 consts + ~35 temps ≈ 60 VGPR — safely under the
// 128-VGPR tier the allocator targets (rounds 3-6 all spilled above it).
// blockIdx.x = (rowblk * JS1 + js) * NH + h ; grid = (N/16)*JS1*NH = 4096
#define TJ 512
#define JS1 2
__global__ __launch_bounds__(512) void k3_attn1(
    const ull* __restrict__ mask, const float* __restrict__ f2p,
    const uint4* __restrict__ hpk, const float* __restrict__ f1a,
    const unsigned* __restrict__ amax, float* __restrict__ part1) {
    __shared__ float tF2[TJ];   // 2 KB
    __shared__ uint4 tH[TJ];    // 8 KB
    int tid = threadIdx.x;
    int lane = tid & 63;
    int wave = tid >> 6;
    int h = blockIdx.x & 3;
    int js = (blockIdx.x >> 2) & (JS1 - 1);
    int rowblk = blockIdx.x >> 3;
    int r0 = rowblk * 16 + wave * 2;
    int r1 = r0 + 1;
    const int JR = N / JS1;     // 4096
    int jbase = js * JR;

    float mf = fdec(amax[h]);
    float f1 = f1a[r0 * 4 + h];
    float v = f1 + mf, m = fmaxf(v, ALPHA * v);
    float f1m0 = f1 - m, f1q0 = ALPHA * f1 - m;
    f1 = f1a[r1 * 4 + h];
    v = f1 + mf; m = fmaxf(v, ALPHA * v);
    float f1m1 = f1 - m, f1q1 = ALPHA * f1 - m;

    float acc0[FH], acc1[FH], d0 = 0.f, d1 = 0.f;
#pragma unroll
    for (int k = 0; k < FH; k++) { acc0[k] = 0.f; acc1[k] = 0.f; }

    const ull* mr0 = mask + (size_t)r0 * NW;
    const ull* mr1 = mask + (size_t)r1 * NW;

    for (int t = 0; t < JR / TJ; t++) {   // 8
        __syncthreads();
        int gb = jbase + t * TJ + tid;
        tH[tid] = hpk[h * N + gb];
        tF2[tid] = f2p[h * N + gb];
        __syncthreads();
        int wb = (jbase >> 6) + t * (TJ / 64);
#pragma unroll
        for (int s = 0; s < TJ / 64; s++) {   // 8
            ull mw0 = mr0[wb + s];
            ull mw1 = mr1[wb + s];
            bool b0 = (mw0 >> lane) & 1ull;
            bool b1 = (mw1 >> lane) & 1ull;
            int jl = s * 64 + lane;
            float f2 = tF2[jl];
            uint4 hq = tH[jl];
            float2 hv01 = bfpair(hq.x);
            float2 hv23 = bfpair(hq.y);
            float2 hv45 = bfpair(hq.z);
            float2 hv67 = bfpair(hq.w);
            float p = ALPHA * f2;
            float w0 = __builtin_amdgcn_exp2f(fmaxf(f1m0 + f2, p + f1q0));
            w0 = b0 ? w0 : 0.f;
            float w1 = __builtin_amdgcn_exp2f(fmaxf(f1m1 + f2, p + f1q1));
            w1 = b1 ? w1 : 0.f;
            acc0[0] = fmaf(w0, hv01.x, acc0[0]);
            acc0[1] = fmaf(w0, hv01.y, acc0[1]);
            acc0[2] = fmaf(w0, hv23.x, acc0[2]);
            acc0[3] = fmaf(w0, hv23.y, acc0[3]);
            acc0[4] = fmaf(w0, hv45.x, acc0[4]);
            acc0[5] = fmaf(w0, hv45.y, acc0[5]);
            acc0[6] = fmaf(w0, hv67.x, acc0[6]);
            acc0[7] = fmaf(w0, hv67.y, acc0[7]);
            d0 += w0;
            acc1[0] = fmaf(w1, hv01.x, acc1[0]);
            acc1[1] = fmaf(w1, hv01.y, acc1[1]);
            acc1[2] = fmaf(w1, hv23.x, acc1[2]);
            acc1[3] = fmaf(w1, hv23.y, acc1[3]);
            acc1[4] = fmaf(w1, hv45.x, acc1[4]);
            acc1[5] = fmaf(w1, hv45.y, acc1[5]);
            acc1[6] = fmaf(w1, hv67.x, acc1[6]);
            acc1[7] = fmaf(w1, hv67.y, acc1[7]);
            d1 += w1;
        }
    }
#pragma unroll
    for (int k = 0; k < FH; k++) {
        for (int off = 32; off > 0; off >>= 1) {
            acc0[k] += __shfl_xor(acc0[k], off, 64);
            acc1[k] += __shfl_xor(acc1[k], off, 64);
        }
    }
    for (int off = 32; off > 0; off >>= 1) {
        d0 += __shfl_xor(d0, off, 64);
        d1 += __shfl_xor(d1, off, 64);
    }
    if (lane == 0) {
#pragma unroll
        for (int k = 0; k < FH; k++) {
            part1[(js * 36 + h * 9 + k) * N + r0] = acc0[k];
            part1[(js * 36 + h * 9 + k) * N + r1] = acc1[k];
        }
        part1[(js * 36 + h * 9 + 8) * N + r0] = d0;
        part1[(js * 36 + h * 9 + 8) * N + r1] = d1;
    }
}

// ---------------- K3b: finalize layer 1 + layer-2 features + fused layer-2 max ----------------
__global__ void k3b_final(const float* __restrict__ part1, const float* __restrict__ Wo,
                          const float* __restrict__ ao,
                          float4* __restrict__ rec2, float* __restrict__ f1b,
                          unsigned* __restrict__ amax) {
    __shared__ float sW[64];
    __shared__ float sa[4];
    int tid = threadIdx.x;
    if (tid < 64) sW[tid] = Wo[tid];
    if (tid < 4) sa[tid] = ao[tid];
    __syncthreads();
    int row = blockIdx.x * 256 + tid;
    float hv[32];
#pragma unroll
    for (int h = 0; h < NH; h++) {
        float s[9];
#pragma unroll
        for (int c = 0; c < 9; c++)
            s[c] = part1[(h * 9 + c) * N + row] + part1[(36 + h * 9 + c) * N + row];
        float inv = 1.f / s[8];
#pragma unroll
        for (int k = 0; k < FH; k++) {
            float o = s[k] * inv;
            hv[h * 8 + k] = (o > 0.f) ? o : expm1f(o);
        }
    }
    float h0 = 0.f, h1 = 0.f;
#pragma unroll
    for (int i = 0; i < 32; i++) {
        h0 = fmaf(hv[i], sW[i * 2 + 0], h0);
        h1 = fmaf(hv[i], sW[i * 2 + 1], h1);
    }
    float f1 = (h0 * sa[0] + h1 * sa[1]) * LOG2E;
    float f2 = (h0 * sa[2] + h1 * sa[3]) * LOG2E;
    rec2[row] = make_float4(f2, h0, h1, 0.f);
    f1b[row] = f1;
    float vmax = f2;
    for (int off = 32; off > 0; off >>= 1) vmax = fmaxf(vmax, __shfl_xor(vmax, off, 64));
    if ((tid & 63) == 0) atomicMax(&amax[4], fenc(vmax));
}

// ---------------- K6: layer-2 attention partials — no LDS, no barriers ----------------
// rec2 (128 KB) is L2-resident: stream float4 straight from global.
#define JS2 4
__global__ __launch_bounds__(256) void k6_attn2(
    const ull* __restrict__ mask, const float4* __restrict__ rec2,
    const float* __restrict__ f1b, const unsigned* __restrict__ amax,
    float* __restrict__ part2) {
    int tid = threadIdx.x;
    int lane = tid & 63;
    int wave = tid >> 6;
    int blk = blockIdx.x >> 2;
    int js = blockIdx.x & 3;
    int rbase = blk * 16 + wave * 4;
    const int JR = N / JS2;   // 2048
    int jbase = js * JR;

    float mb = fdec(amax[4]);
    float f1m[4], f1q[4];
#pragma unroll
    for (int i = 0; i < 4; i++) {
        float f1 = f1b[rbase + i];
        float v = f1 + mb, m = fmaxf(v, ALPHA * v);
        f1m[i] = f1 - m; f1q[i] = ALPHA * f1 - m;
    }
    float a0[4] = {0.f, 0.f, 0.f, 0.f};
    float a1[4] = {0.f, 0.f, 0.f, 0.f};
    float dd[4] = {0.f, 0.f, 0.f, 0.f};
    const ull* mr[4];
#pragma unroll
    for (int i = 0; i < 4; i++) mr[i] = mask + (size_t)(rbase + i) * NW;

    int wb = jbase >> 6;
#pragma unroll 4
    for (int s = 0; s < JR / 64; s++) {   // 32
        float4 q = rec2[jbase + s * 64 + lane];
        float p = ALPHA * q.x;
#pragma unroll
        for (int i = 0; i < 4; i++) {
            ull mw = mr[i][wb + s];
            float w = __builtin_amdgcn_exp2f(fmaxf(f1m[i] + q.x, p + f1q[i]));
            w = ((mw >> lane) & 1ull) ? w : 0.f;
            a0[i] = fmaf(w, q.y, a0[i]);
            a1[i] = fmaf(w, q.z, a1[i]);
            dd[i] += w;
        }
    }
#pragma unroll
    for (int i = 0; i < 4; i++) {
        for (int off = 32; off > 0; off >>= 1) {
            a0[i] += __shfl_xor(a0[i], off, 64);
            a1[i] += __shfl_xor(a1[i], off, 64);
            dd[i] += __shfl_xor(dd[i], off, 64);
        }
    }
    if (lane == 0) {
#pragma unroll
        for (int i = 0; i < 4; i++) {
            int row = rbase + i;
            part2[(js * 3 + 0) * N + row] = a0[i];
            part2[(js * 3 + 1) * N + row] = a1[i];
            part2[(js * 3 + 2) * N + row] = dd[i];
        }
    }
}

// ---------------- K6b: finalize layer 2 + log_softmax ----------------
__global__ void k6b_final(const float* __restrict__ part2, float* __restrict__ out) {
    int row = blockIdx.x * 256 + threadIdx.x;
    float s0 = 0.f, s1 = 0.f, d = 0.f;
#pragma unroll
    for (int js = 0; js < JS2; js++) {
        s0 += part2[(js * 3 + 0) * N + row];
        s1 += part2[(js * 3 + 1) * N + row];
        d  += part2[(js * 3 + 2) * N + row];
    }
    float inv = 1.f / d;
    float e0 = s0 * inv, e1 = s1 * inv;
    e0 = (e0 > 0.f) ? e0 : expm1f(e0);
    e1 = (e1 > 0.f) ? e1 : expm1f(e1);
    float mx = fmaxf(e0, e1);
    float lse = mx + logf(expf(e0 - mx) + expf(e1 - mx));
    ((float2*)out)[row] = make_float2(e0 - lse, e1 - lse);
}

extern "C" void kernel_launch(void* const* d_in, const int* in_sizes, int n_in,
                              void* d_out, int out_size, void* d_ws, size_t ws_size,
                              hipStream_t stream) {
    const float* x   = (const float*)d_in[0];
    const int*   adj = (const int*)d_in[1];
    const float* Wh  = (const float*)d_in[2];
    const float* ah  = (const float*)d_in[3];
    const float* Wo  = (const float*)d_in[4];
    const float* ao  = (const float*)d_in[5];
    float* out = (float*)d_out;
    float* ws = (float*)d_ws;

    // workspace layout (float offsets)
    ull*      mask  = (ull*)ws;                       // 8 MB = 2097152 floats
    float*    f2p   = ws + 2097152;                   // 4*N
    uint4*    hpk   = (uint4*)(ws + 2129920);         // 4*N uint4 = 131072 floats
    float*    f1a   = ws + 2260992;                   // 4*N
    float*    part1 = ws + 2293760;                   // 2*36*N = 589824
    float4*   rec2  = (float4*)(ws + 2883584);        // N float4
    float*    f1b   = ws + 2916352;                   // N
    float*    part2 = ws + 2924544;                   // 12*N = 98304
    unsigned* amax  = (unsigned*)(ws + 3022848);      // 8 slots (0..3 heads, 4 layer2)

    k0_pack<<<N, 256, 0, stream>>>(adj, mask, amax);
    k1_feat<<<N / 64, 64, 0, stream>>>(x, Wh, ah, f2p, hpk, f1a, amax);
    k3_attn1<<<(N / 16) * JS1 * NH, 512, 0, stream>>>(mask, f2p, hpk, f1a, amax, part1);
    k3b_final<<<N / 256, 256, 0, stream>>>(part1, Wo, ao, rec2, f1b, amax);
    k6_attn2<<<(N / 16) * JS2, 256, 0, stream>>>(mask, rec2, f1b, amax, part2);
    k6b_final<<<N / 256, 256, 0, stream>>>(part2, out);
}